// Round 5
// baseline (673.695 us; speedup 1.0000x reference)
//
#include <hip/hip_runtime.h>
#include <hip/hip_bf16.h>
#include <math.h>

// ---------------- constants ----------------
namespace {
constexpr int Bc   = 2;
constexpr int Nn   = 2048;
constexpr int CACHE= 512;
constexpr int KVL  = 2560;      // CACHE + Nn
constexpr int DM   = 768;
constexpr int NH   = 12;
constexpr int HD   = 64;
constexpr int FFD  = 3072;
constexpr int RR   = Bc * Nn;   // 4096 rows
}
#define EPSF 1e-5f

typedef unsigned short u16;
typedef __bf16 bf16x8 __attribute__((ext_vector_type(8)));
typedef float  f32x4  __attribute__((ext_vector_type(4)));
typedef u16    u16x8  __attribute__((ext_vector_type(8)));
typedef u16    u16x4  __attribute__((ext_vector_type(4)));

#define GPTR(p) ((const __attribute__((address_space(1))) void*)(p))
#define LPTR(p) ((__attribute__((address_space(3))) void*)(p))

// ---------------- helpers ----------------
__device__ __forceinline__ float geluf(float x) {
  float x3 = x * x * x;
  float t  = tanhf(0.7978845608028654f * (x + 0.044715f * x3));
  return 0.5f * x * (1.0f + t);
}
__device__ __forceinline__ float sigmoidf_(float x) {
  return 1.0f / (1.0f + __expf(-x));
}
__device__ __forceinline__ u16 f2bf(float x) {
  union { float f; unsigned u; } v; v.f = x;
  unsigned r = (v.u + 0x7fffu + ((v.u >> 16) & 1u)) >> 16;
  return (u16)r;
}
__device__ __forceinline__ float bf2f(u16 u) {
  union { unsigned u; float f; } v; v.u = ((unsigned)u) << 16;
  return v.f;
}

// ---------------- rmsnorm: one block per row; bf16 or fp32 out ----------------
template<bool BF>
__global__ __launch_bounds__(256) void k_rmsnorm2(const float* __restrict__ in,
                                                  const float* __restrict__ w,
                                                  void* __restrict__ outv, int D) {
  const int row = blockIdx.x;
  const float* x = in + (size_t)row * D;
  float ss = 0.f;
  for (int i = threadIdx.x; i < D; i += 256) { float v = x[i]; ss = fmaf(v, v, ss); }
  __shared__ float red[5];
#pragma unroll
  for (int off = 32; off > 0; off >>= 1) ss += __shfl_down(ss, off, 64);
  if ((threadIdx.x & 63) == 0) red[threadIdx.x >> 6] = ss;
  __syncthreads();
  if (threadIdx.x == 0) red[4] = red[0] + red[1] + red[2] + red[3];
  __syncthreads();
  const float scale = rsqrtf(red[4] * (1.0f / (float)D) + EPSF);
  for (int i = threadIdx.x; i < D; i += 256) {
    const float v = x[i] * scale * w[i];
    if (BF) ((u16*)outv)[(size_t)row * D + i] = f2bf(v);
    else    ((float*)outv)[(size_t)row * D + i] = v;
  }
}

// ---------------- weight prep: W (K x N) f32 -> Wt (N x K) bf16 ----------------
__global__ __launch_bounds__(256) void k_wt(const float* __restrict__ W,
                                            u16* __restrict__ Wt, int K, int N) {
  __shared__ __align__(16) u16 T[64][72];
  const int nb = blockIdx.x * 64;
  const int kb = blockIdx.y * 64;
#pragma unroll
  for (int p = 0; p < 4; ++p) {
    const int r = p * 16 + (threadIdx.x >> 4);      // k within tile
    const int c = (threadIdx.x & 15) * 4;           // n within tile
    float4 v = *(const float4*)(W + (size_t)(kb + r) * N + nb + c);
    T[c + 0][r] = f2bf(v.x); T[c + 1][r] = f2bf(v.y);
    T[c + 2][r] = f2bf(v.z); T[c + 3][r] = f2bf(v.w);
  }
  __syncthreads();
  const int cc = (threadIdx.x & 7) * 8;
#pragma unroll
  for (int p = 0; p < 2; ++p) {
    const int rr = p * 32 + (threadIdx.x >> 3);
    *(u16x8*)(Wt + (size_t)(nb + rr) * K + kb + cc) = *(const u16x8*)&T[rr][cc];
  }
}

// ---------------- MFMA GEMM: BM=128, BK=64, XOR-swizzled LDS ------------------
// C[M x Nc] = A[M x K]bf16 @ Wt[Nc x K]^T. MODE: 0=+bias, 1=gelu, 2=0.5+res, 3=+res.
// Epilogue: LDS transpose -> 16B coalesced stores (store-issue was the R4 limit).
template<int BN, int MODE, bool OUTBF>
__global__ __launch_bounds__(256) void k_gemm_mfma(const u16* __restrict__ A,
                                                   const u16* __restrict__ Wt,
                                                   const float* __restrict__ bias,
                                                   const float* __restrict__ res,
                                                   void* __restrict__ Cv,
                                                   int K, int Nc) {
  constexpr int BM = 128, BK = 64;
  constexpr int CT = BN / 32;
  constexpr int STAGE = (BM + BN) * BK;       // u16 units
  constexpr int EPI   = BN * 72 * 2;          // u16 units (float T[BN][72])
  __shared__ __align__(16) u16 smem[(STAGE > EPI) ? STAGE : EPI];
  u16* As = smem;
  u16* Bs = smem + BM * BK;
  const int lane = threadIdx.x & 63;
  const int w    = threadIdx.x >> 6;
  const int rowBase = blockIdx.y * BM;
  const int colBase = blockIdx.x * BN;
  const int l15 = lane & 15, quad = lane >> 4;
  const int wr = w >> 1, wc = w & 1;
  const int sw = l15 & 7;

  f32x4 acc[4][CT];
#pragma unroll
  for (int i = 0; i < 4; ++i)
#pragma unroll
    for (int j = 0; j < CT; ++j) acc[i][j] = (f32x4){0.f, 0.f, 0.f, 0.f};

  for (int k0 = 0; k0 < K; k0 += BK) {
#pragma unroll
    for (int s = 0; s < 4; ++s) {
      const int cbase = (w * 4 + s) * 64;
      const int c = cbase + lane;
      const int r = c >> 3;
      const int kc = (c & 7) ^ (r & 7);
      __builtin_amdgcn_global_load_lds(
          GPTR(A + (size_t)(rowBase + r) * K + k0 + kc * 8),
          LPTR((char*)As + (size_t)cbase * 16), 16, 0, 0);
    }
#pragma unroll
    for (int s = 0; s < BN / 32; ++s) {
      const int cbase = (w * (BN / 32) + s) * 64;
      const int c = cbase + lane;
      const int r = c >> 3;
      const int kc = (c & 7) ^ (r & 7);
      __builtin_amdgcn_global_load_lds(
          GPTR(Wt + (size_t)(colBase + r) * K + k0 + kc * 8),
          LPTR((char*)Bs + (size_t)cbase * 16), 16, 0, 0);
    }
    __syncthreads();

#pragma unroll
    for (int kk = 0; kk < 2; ++kk) {
      bf16x8 aF[4], bF[CT];
#pragma unroll
      for (int rt = 0; rt < 4; ++rt) {
        const int row = wr * 64 + rt * 16 + l15;
        aF[rt] = *(const bf16x8*)&As[row * BK + (((kk * 4 + quad) ^ sw) * 8)];
      }
#pragma unroll
      for (int ct = 0; ct < CT; ++ct) {
        const int row = wc * (BN / 2) + ct * 16 + l15;
        bF[ct] = *(const bf16x8*)&Bs[row * BK + (((kk * 4 + quad) ^ sw) * 8)];
      }
#pragma unroll
      for (int rt = 0; rt < 4; ++rt)
#pragma unroll
        for (int ct = 0; ct < CT; ++ct)
          acc[rt][ct] = __builtin_amdgcn_mfma_f32_16x16x32_bf16(aF[rt], bF[ct],
                                                                acc[rt][ct], 0, 0, 0);
    }
    __syncthreads();
  }

  // ---- epilogue: two row-half passes through LDS transpose tile ----
  float* Tf = (float*)smem;                    // T[col][72], col in [0,BN)
#pragma unroll
  for (int p = 0; p < 2; ++p) {
    __syncthreads();
#pragma unroll
    for (int rt2 = 0; rt2 < 2; ++rt2) {
      const int rt = p * 2 + rt2;
#pragma unroll
      for (int ct = 0; ct < CT; ++ct) {
        const int col = wc * (BN / 2) + ct * 16 + l15;
        const int rowp = wr * 32 + rt2 * 16 + quad * 4;
        *(f32x4*)&Tf[col * 72 + rowp] = acc[rt][ct];
      }
    }
    __syncthreads();
    constexpr int ITER = (64 * (BN / 8)) / 256;
#pragma unroll
    for (int it = 0; it < ITER; ++it) {
      const int idx = it * 256 + threadIdx.x;
      const int row = idx & 63;
      const int g = idx >> 6;
      const int grow = rowBase + (row >> 5) * 64 + p * 32 + (row & 31);
      const int gcol = colBase + g * 8;
      float v[8];
#pragma unroll
      for (int j = 0; j < 8; ++j) v[j] = Tf[(g * 8 + j) * 72 + row];
      if (bias) {
        const float4 b0 = *(const float4*)(bias + gcol);
        const float4 b1 = *(const float4*)(bias + gcol + 4);
        v[0] += b0.x; v[1] += b0.y; v[2] += b0.z; v[3] += b0.w;
        v[4] += b1.x; v[5] += b1.y; v[6] += b1.z; v[7] += b1.w;
      }
      if (MODE == 1) {
#pragma unroll
        for (int j = 0; j < 8; ++j) v[j] = geluf(v[j]);
      } else if (MODE == 2 || MODE == 3) {
        const float sc = (MODE == 2) ? 0.5f : 1.0f;
        const float4 r0 = *(const float4*)(res + (size_t)grow * Nc + gcol);
        const float4 r1 = *(const float4*)(res + (size_t)grow * Nc + gcol + 4);
        v[0] = fmaf(sc, v[0], r0.x); v[1] = fmaf(sc, v[1], r0.y);
        v[2] = fmaf(sc, v[2], r0.z); v[3] = fmaf(sc, v[3], r0.w);
        v[4] = fmaf(sc, v[4], r1.x); v[5] = fmaf(sc, v[5], r1.y);
        v[6] = fmaf(sc, v[6], r1.z); v[7] = fmaf(sc, v[7], r1.w);
      }
      if (OUTBF) {
        u16x8 o;
#pragma unroll
        for (int j = 0; j < 8; ++j) o[j] = f2bf(v[j]);
        *(u16x8*)((u16*)Cv + (size_t)grow * Nc + gcol) = o;
      } else {
        float* cp = (float*)Cv + (size_t)grow * Nc + gcol;
        *(float4*)cp = make_float4(v[0], v[1], v[2], v[3]);
        *(float4*)(cp + 4) = make_float4(v[4], v[5], v[6], v[7]);
      }
    }
  }
}

// ---------------- qkv split + q/k rmsnorm + RoPE + kv emit (fused) ------------
// qbf is pre-scaled by 0.125 (attention scale folded in).
__global__ __launch_bounds__(768) void k_qkv_post(const float* __restrict__ qkv,
                                                  const float* __restrict__ qw,
                                                  const float* __restrict__ kw,
                                                  u16* __restrict__ qbf,
                                                  u16* __restrict__ krotbf,
                                                  float* __restrict__ kvout) {
  const int row = blockIdx.x;             // b*Nn + n
  const int b = row >> 11;
  const int n = row & 2047;
  const int h = threadIdx.x >> 6;
  const int d = threadIdx.x & 63;
  const float* src = qkv + (size_t)row * (3 * DM) + h * 192 + d * 3;
  const float q = src[0], k = src[1], v = src[2];
  float sq = q * q, sk = k * k;
#pragma unroll
  for (int off = 32; off > 0; off >>= 1) {
    sq += __shfl_xor(sq, off, 64);
    sk += __shfl_xor(sk, off, 64);
  }
  const float qs = rsqrtf(sq * (1.0f / 64.0f) + EPSF);
  const float ks = rsqrtf(sk * (1.0f / 64.0f) + EPSF);
  const float qn = q * qs * qw[d];
  const float kn = k * ks * kw[d];
  const size_t kvbase = ((size_t)b * KVL + (CACHE + n)) * (2 * DM) + h * 64 + d;
  kvout[kvbase] = kn;
  kvout[kvbase + DM] = v;
  const int j = d & 31;
  const float inv = powf(10000.0f, -(float)j * (1.0f / 32.0f));
  float s, c;
  sincosf((float)(CACHE + n) * inv, &s, &c);
  const float oq = __shfl_xor(qn, 32, 64);
  const float ok = __shfl_xor(kn, 32, 64);
  const float rq = (d < 32) ? -oq : oq;
  const float rk = (d < 32) ? -ok : ok;
  qbf[((size_t)row * NH + h) * 64 + d] = f2bf((qn * c + rq * s) * 0.125f);
  krotbf[((size_t)(b * KVL + CACHE + n) * NH + h) * 64 + d] = f2bf(kn * c + rk * s);
}

// ---------------- cache rows: copy to out_kv + RoPE k (fused) -----------------
__global__ __launch_bounds__(768) void k_cache_prep(const float* __restrict__ cached,
                                                    float* __restrict__ kvout,
                                                    u16* __restrict__ krotbf) {
  const int row = blockIdx.x;            // b*CACHE + t
  const int b = row / CACHE, t = row - b * CACHE;
  const int h = threadIdx.x >> 6;
  const int d = threadIdx.x & 63;
  const float k = cached[((size_t)row * 2 + 0) * DM + h * 64 + d];
  const float v = cached[((size_t)row * 2 + 1) * DM + h * 64 + d];
  const size_t kb = ((size_t)b * KVL + t) * (2 * DM) + h * 64 + d;
  kvout[kb] = k;
  kvout[kb + DM] = v;
  const int j = d & 31;
  const float inv = powf(10000.0f, -(float)j * (1.0f / 32.0f));
  float s, c;
  sincosf((float)t * inv, &s, &c);
  const float ok = __shfl_xor(k, 32, 64);
  const float rk = (d < 32) ? -ok : ok;
  krotbf[((size_t)(b * KVL + t) * NH + h) * 64 + d] = f2bf(k * c + rk * s);
}

// ---------------- V transpose: (B,KVL,H,64) f32 -> vtbf (B,H,64,KVL) bf16 ----
__global__ __launch_bounds__(256) void k_vt(const float* __restrict__ kvout,
                                            u16* __restrict__ vtbf) {
  __shared__ __align__(16) u16 T[64][72];
  const int bh = blockIdx.x / 40;
  const int tb = blockIdx.x % 40;
  const int b = bh / NH, h = bh % NH;
  const int t0 = tb * 64;
  {
    const int tloc = threadIdx.x >> 2;
    const int dg = (threadIdx.x & 3) * 16;
    const float* src = kvout + ((size_t)b * KVL + t0 + tloc) * (2 * DM) + DM + h * 64 + dg;
    float4 v0 = *(const float4*)(src);
    float4 v1 = *(const float4*)(src + 4);
    float4 v2 = *(const float4*)(src + 8);
    float4 v3 = *(const float4*)(src + 12);
    T[dg + 0][tloc] = f2bf(v0.x);  T[dg + 1][tloc] = f2bf(v0.y);
    T[dg + 2][tloc] = f2bf(v0.z);  T[dg + 3][tloc] = f2bf(v0.w);
    T[dg + 4][tloc] = f2bf(v1.x);  T[dg + 5][tloc] = f2bf(v1.y);
    T[dg + 6][tloc] = f2bf(v1.z);  T[dg + 7][tloc] = f2bf(v1.w);
    T[dg + 8][tloc] = f2bf(v2.x);  T[dg + 9][tloc] = f2bf(v2.y);
    T[dg + 10][tloc] = f2bf(v2.z); T[dg + 11][tloc] = f2bf(v2.w);
    T[dg + 12][tloc] = f2bf(v3.x); T[dg + 13][tloc] = f2bf(v3.y);
    T[dg + 14][tloc] = f2bf(v3.z); T[dg + 15][tloc] = f2bf(v3.w);
  }
  __syncthreads();
  const int d = threadIdx.x >> 2;
  const int kg = (threadIdx.x & 3) * 16;
  u16x8 a = *(const u16x8*)&T[d][kg];
  u16x8 b8 = *(const u16x8*)&T[d][kg + 8];
  u16* dst = vtbf + ((size_t)(b * NH + h) * 64 + d) * KVL + t0 + kg;
  *(u16x8*)dst = a;
  *(u16x8*)(dst + 8) = b8;
}

// ---------------- MFMA flash attention v2 ----------------
__global__ __launch_bounds__(256) void k_attn2(const u16* __restrict__ qbf,
                                               const u16* __restrict__ krotbf,
                                               const u16* __restrict__ vtbf,
                                               float* __restrict__ Apart,
                                               float* __restrict__ lpart) {
  __shared__ __align__(16) u16 Ks[64 * 64];
  __shared__ __align__(16) u16 Vs[64 * 64];
  __shared__ __align__(16) u16 Ps[4][16][80];
  const int lane = threadIdx.x & 63;
  const int wid  = threadIdx.x >> 6;
  const int sp   = blockIdx.x & 1;
  const int rest = blockIdx.x >> 1;
  const int qblk = rest & 31;
  const int bh   = rest >> 5;
  const int b = bh / NH, h = bh % NH;
  const int q0 = qblk * 64 + wid * 16;
  const int l15 = lane & 15;
  const int quad = lane >> 4;
  const int sw = l15 & 7;

  const u16* qp = qbf + ((size_t)(b * Nn + q0 + l15) * NH + h) * 64 + quad * 8;
  const bf16x8 bQ0 = *(const bf16x8*)qp;
  const bf16x8 bQ1 = *(const bf16x8*)(qp + 32);

  f32x4 O[4] = {};
  float l_lane = 0.f;

  const u16* kbase = krotbf + ((size_t)b * KVL * NH + h) * 64;
  const u16* vbase = vtbf + ((size_t)(b * NH + h) * 64) * KVL;

  const int tbeg = sp * (KVL / 2);
  for (int t0 = tbeg; t0 < tbeg + KVL / 2; t0 += 64) {
    __syncthreads();
#pragma unroll
    for (int it = 0; it < 2; ++it) {
      const int cbase = (wid * 2 + it) * 64;
      const int c = cbase + lane;
      const int r = c >> 3;
      const int kc = (c & 7) ^ (r & 7);
      __builtin_amdgcn_global_load_lds(
          GPTR(kbase + (size_t)(t0 + r) * (NH * 64) + kc * 8),
          LPTR((char*)Ks + (size_t)cbase * 16), 16, 0, 0);
      __builtin_amdgcn_global_load_lds(
          GPTR(vbase + (size_t)r * KVL + t0 + kc * 8),
          LPTR((char*)Vs + (size_t)cbase * 16), 16, 0, 0);
    }
    __syncthreads();

#pragma unroll
    for (int nt = 0; nt < 4; ++nt) {
      const int krow = nt * 16 + l15;
      const bf16x8 aK0 = *(const bf16x8*)&Ks[krow * 64 + ((quad ^ sw) * 8)];
      const bf16x8 aK1 = *(const bf16x8*)&Ks[krow * 64 + (((4 + quad) ^ sw) * 8)];
      f32x4 cc = {};
      cc = __builtin_amdgcn_mfma_f32_16x16x32_bf16(aK0, bQ0, cc, 0, 0, 0);
      cc = __builtin_amdgcn_mfma_f32_16x16x32_bf16(aK1, bQ1, cc, 0, 0, 0);
      const float p0 = __expf(cc[0]);
      const float p1 = __expf(cc[1]);
      const float p2 = __expf(cc[2]);
      const float p3 = __expf(cc[3]);
      l_lane += (p0 + p1) + (p2 + p3);
      uint2 pk;
      pk.x = (unsigned)f2bf(p0) | ((unsigned)f2bf(p1) << 16);
      pk.y = (unsigned)f2bf(p2) | ((unsigned)f2bf(p3) << 16);
      *(uint2*)&Ps[wid][l15][nt * 16 + quad * 4] = pk;
    }
    asm volatile("s_waitcnt lgkmcnt(0)" ::: "memory");

#pragma unroll
    for (int kt = 0; kt < 2; ++kt) {
      const bf16x8 bP = *(const bf16x8*)&Ps[wid][l15][kt * 32 + quad * 8];
#pragma unroll
      for (int ot = 0; ot < 4; ++ot) {
        const int vrow = ot * 16 + l15;
        const bf16x8 aV = *(const bf16x8*)&Vs[vrow * 64 + (((kt * 4 + quad) ^ sw) * 8)];
        O[ot] = __builtin_amdgcn_mfma_f32_16x16x32_bf16(aV, bP, O[ot], 0, 0, 0);
      }
    }
  }

  l_lane += __shfl_xor(l_lane, 16, 64);
  l_lane += __shfl_xor(l_lane, 32, 64);
  const int sbh = (sp * Bc + b) * NH + h;
  if (quad == 0) lpart[(size_t)sbh * Nn + q0 + l15] = l_lane;
  float* ap = Apart + ((size_t)sbh * 64) * Nn + q0 + l15;
#pragma unroll
  for (int ot = 0; ot < 4; ++ot)
#pragma unroll
    for (int r = 0; r < 4; ++r)
      ap[(size_t)(ot * 16 + quad * 4 + r) * Nn] = O[ot][r];
}

// ---------------- attention merge: combine splits, normalize, transpose -------
__global__ __launch_bounds__(256) void k_attn_merge(const float* __restrict__ Apart,
                                                    const float* __restrict__ lpart,
                                                    u16* __restrict__ attnout) {
  __shared__ float T[64][65];
  __shared__ float il[64];
  const int qt = blockIdx.x & 31;
  const int bh = blockIdx.x >> 5;
  const int b = bh / NH, h = bh % NH;
  const int q0 = qt * 64;
  const int bh0 = b * NH + h;
  const int bh1 = (Bc + b) * NH + h;
  if (threadIdx.x < 64) {
    const int q = threadIdx.x;
    il[q] = 1.0f / (lpart[(size_t)bh0 * Nn + q0 + q] + lpart[(size_t)bh1 * Nn + q0 + q]);
  }
  const float* a0 = Apart + ((size_t)bh0 * 64) * Nn + q0;
  const float* a1 = Apart + ((size_t)bh1 * 64) * Nn + q0;
#pragma unroll
  for (int p = 0; p < 16; ++p) {
    const int idx = p * 256 + threadIdx.x;
    const int d = idx >> 6, q = idx & 63;
    T[q][d] = a0[(size_t)d * Nn + q] + a1[(size_t)d * Nn + q];
  }
  __syncthreads();
#pragma unroll
  for (int p = 0; p < 16; ++p) {
    const int idx = p * 256 + threadIdx.x;
    const int q = idx >> 6, d = idx & 63;
    attnout[((size_t)(b * Nn + q0 + q)) * DM + h * 64 + d] = f2bf(T[q][d] * il[q]);
  }
}

// ---------------- fused GLU + depthwise conv + BN partial stats ----------------
__global__ __launch_bounds__(256) void k_dwconv2(const u16* __restrict__ pw1,
                                                 const float* __restrict__ w,
                                                 const float* __restrict__ bsd,
                                                 float* __restrict__ out,
                                                 float* __restrict__ stats) {
  __shared__ float S[94][68];
  __shared__ float Wl[31][64];
  const int cb = blockIdx.x * 64;
  const int n0 = blockIdx.y * 64;
  const int b  = blockIdx.z;
  for (int idx = threadIdx.x; idx < 94 * 16; idx += 256) {
    const int r = idx >> 4, cg = (idx & 15) * 4;
    const int n = n0 - 15 + r;
    float4 v = make_float4(0.f, 0.f, 0.f, 0.f);
    if (n >= 0 && n < Nn) {
      const u16* p = pw1 + ((size_t)(b * Nn + n)) * (2 * DM) + cb + cg;
      u16x4 av = *(const u16x4*)(p);
      u16x4 gv = *(const u16x4*)(p + DM);
      v.x = bf2f(av[0]) * sigmoidf_(bf2f(gv[0]));
      v.y = bf2f(av[1]) * sigmoidf_(bf2f(gv[1]));
      v.z = bf2f(av[2]) * sigmoidf_(bf2f(gv[2]));
      v.w = bf2f(av[3]) * sigmoidf_(bf2f(gv[3]));
    }
    *(float4*)&S[r][cg] = v;
  }
  for (int idx = threadIdx.x; idx < 31 * 64; idx += 256) {
    const int c = idx & 63, tap = idx >> 6;
    Wl[tap][c] = w[(size_t)(cb + c) * 31 + tap];
  }
  __syncthreads();

  const int cg  = (threadIdx.x & 15) * 4;
  const int nl0 = threadIdx.x >> 4;
  const float4 b4 = *(const float4*)(bsd + cb + cg);
  float sum[4] = {0.f, 0.f, 0.f, 0.f};
  float sq[4]  = {0.f, 0.f, 0.f, 0.f};
#pragma unroll
  for (int p = 0; p < 4; ++p) {
    const int nl = p * 16 + nl0;
    float a0 = b4.x, a1 = b4.y, a2 = b4.z, a3 = b4.w;
#pragma unroll
    for (int t = 0; t < 31; ++t) {
      const float4 sv = *(const float4*)&S[nl + t][cg];
      const float4 wv = *(const float4*)&Wl[t][cg & 63];
      a0 = fmaf(sv.x, wv.x, a0); a1 = fmaf(sv.y, wv.y, a1);
      a2 = fmaf(sv.z, wv.z, a2); a3 = fmaf(sv.w, wv.w, a3);
    }
    *(float4*)(out + ((size_t)(b * Nn + n0 + nl)) * DM + cb + cg) =
        make_float4(a0, a1, a2, a3);
    sum[0] += a0; sum[1] += a1; sum[2] += a2; sum[3] += a3;
    sq[0] = fmaf(a0, a0, sq[0]); sq[1] = fmaf(a1, a1, sq[1]);
    sq[2] = fmaf(a2, a2, sq[2]); sq[3] = fmaf(a3, a3, sq[3]);
  }
  __syncthreads();
  *(float4*)&S[nl0][cg]      = make_float4(sum[0], sum[1], sum[2], sum[3]);
  *(float4*)&S[16 + nl0][cg] = make_float4(sq[0], sq[1], sq[2], sq[3]);
  __syncthreads();
  if (threadIdx.x < 64) {
    const int c = threadIdx.x;
    float s = 0.f, q = 0.f;
#pragma unroll
    for (int i = 0; i < 16; ++i) { s += S[i][c]; q += S[16 + i][c]; }
    atomicAdd(&stats[cb + c], s);
    atomicAdd(&stats[DM + cb + c], q);
  }
}

__global__ __launch_bounds__(256) void k_zero(float* __restrict__ p, int n) {
  const int i = blockIdx.x * 256 + threadIdx.x;
  if (i < n) p[i] = 0.f;
}

__global__ __launch_bounds__(256) void k_bn_apply(const float* __restrict__ x,
                                                  const float* __restrict__ stats,
                                                  const float* __restrict__ g,
                                                  const float* __restrict__ bb,
                                                  u16* __restrict__ out) {
  const int idx = blockIdx.x * 256 + threadIdx.x;
  const int c = idx % DM;
  const float mean = stats[c] * (1.0f / (float)RR);
  const float var = stats[DM + c] * (1.0f / (float)RR) - mean * mean;
  float y = (x[idx] - mean) * rsqrtf(var + EPSF) * g[c] + bb[c];
  out[idx] = f2bf(y * sigmoidf_(y));
}

// ---------------- launch ----------------
extern "C" void kernel_launch(void* const* d_in, const int* in_sizes, int n_in,
                              void* d_out, int out_size, void* d_ws, size_t ws_size,
                              hipStream_t stream) {
  const float* x       = (const float*)d_in[0];
  const float* cached  = (const float*)d_in[4];
  const float* ff1_nw  = (const float*)d_in[5];
  const float* ff1_w1  = (const float*)d_in[6];
  const float* ff1_b1  = (const float*)d_in[7];
  const float* ff1_w2  = (const float*)d_in[8];
  const float* ff1_b2  = (const float*)d_in[9];
  const float* attn_nw = (const float*)d_in[10];
  const float* qkv_w   = (const float*)d_in[11];
  const float* out_w   = (const float*)d_in[12];
  const float* q_nw    = (const float*)d_in[13];
  const float* k_nw    = (const float*)d_in[14];
  const float* conv_nw = (const float*)d_in[15];
  const float* pw1_w   = (const float*)d_in[16];
  const float* pw1_b   = (const float*)d_in[17];
  const float* dw_w    = (const float*)d_in[18];
  const float* dw_b    = (const float*)d_in[19];
  const float* bn_g    = (const float*)d_in[20];
  const float* bn_b    = (const float*)d_in[21];
  const float* pw2_w   = (const float*)d_in[22];
  const float* pw2_b   = (const float*)d_in[23];
  const float* ff2_nw  = (const float*)d_in[24];
  const float* ff2_w1  = (const float*)d_in[25];
  const float* ff2_b1  = (const float*)d_in[26];
  const float* ff2_w2  = (const float*)d_in[27];
  const float* ff2_b2  = (const float*)d_in[28];
  const float* out_nw  = (const float*)d_in[29];

  float* out_x  = (float*)d_out;
  float* out_kv = out_x + (size_t)RR * DM;

  // ---- workspace layout ----
  u16* wt_ff1w1 = (u16*)d_ws;                          // 3072 x 768
  u16* wt_ff1w2 = wt_ff1w1 + (size_t)3072 * 768;       // 768 x 3072
  u16* wt_qkv   = wt_ff1w2 + (size_t)768 * 3072;       // 2304 x 768
  u16* wt_out   = wt_qkv   + (size_t)2304 * 768;       // 768 x 768
  u16* wt_pw1   = wt_out   + (size_t)768 * 768;        // 1536 x 768
  u16* wt_pw2   = wt_pw1   + (size_t)1536 * 768;       // 768 x 768
  u16* wt_ff2w1 = wt_pw2   + (size_t)768 * 768;        // 3072 x 768
  u16* wt_ff2w2 = wt_ff2w1 + (size_t)3072 * 768;       // 768 x 3072
  u16* abuf     = wt_ff2w2 + (size_t)768 * 3072;       // RR x 768 bf16
  u16* hbuf     = abuf + (size_t)RR * DM;              // RR x 3072 bf16
  float* xA     = (float*)(hbuf + (size_t)RR * FFD);   // RR x 768 f32
  float* xB     = xA + (size_t)RR * DM;                // RR x 768 f32
  float* qkvbuf = xB + (size_t)RR * DM;                // RR x 2304 f32
  u16* qbf      = (u16*)(qkvbuf + (size_t)RR * 3 * DM);
  u16* krotbf   = qbf + (size_t)RR * DM;
  u16* vtbf     = krotbf + (size_t)Bc * KVL * DM;
  float* bn_stats = (float*)(vtbf + (size_t)Bc * KVL * DM);
  // aliases (disjoint lifetimes):
  float* Apart  = (float*)hbuf;
  u16* attnout  = (u16*)qkvbuf;
  float* lpart  = qkvbuf + (size_t)RR * DM;
  float* dwout  = qkvbuf;
  u16* bnout    = (u16*)(qkvbuf + (size_t)RR * DM);

  const dim3 blk(256);
  // ---- weight prep ----
  k_wt<<<dim3(48, 12), blk, 0, stream>>>(ff1_w1, wt_ff1w1, DM, FFD);
  k_wt<<<dim3(12, 48), blk, 0, stream>>>(ff1_w2, wt_ff1w2, FFD, DM);
  k_wt<<<dim3(36, 12), blk, 0, stream>>>(qkv_w, wt_qkv, DM, 3 * DM);
  k_wt<<<dim3(12, 12), blk, 0, stream>>>(out_w, wt_out, DM, DM);
  k_wt<<<dim3(24, 12), blk, 0, stream>>>(pw1_w, wt_pw1, DM, 2 * DM);
  k_wt<<<dim3(12, 12), blk, 0, stream>>>(pw2_w, wt_pw2, DM, DM);
  k_wt<<<dim3(48, 12), blk, 0, stream>>>(ff2_w1, wt_ff2w1, DM, FFD);
  k_wt<<<dim3(12, 48), blk, 0, stream>>>(ff2_w2, wt_ff2w2, FFD, DM);

  // ---- FF1 ----
  k_rmsnorm2<true><<<RR, blk, 0, stream>>>(x, ff1_nw, abuf, DM);
  k_gemm_mfma<128, 1, true><<<dim3(FFD / 128, RR / 128), blk, 0, stream>>>(
      abuf, wt_ff1w1, ff1_b1, nullptr, hbuf, DM, FFD);
  k_gemm_mfma<64, 2, false><<<dim3(DM / 64, RR / 128), blk, 0, stream>>>(
      hbuf, wt_ff1w2, ff1_b2, x, xA, FFD, DM);
  // ---- Attention ----
  k_rmsnorm2<true><<<RR, blk, 0, stream>>>(xA, attn_nw, abuf, DM);
  k_gemm_mfma<128, 0, false><<<dim3(3 * DM / 128, RR / 128), blk, 0, stream>>>(
      abuf, wt_qkv, nullptr, nullptr, qkvbuf, DM, 3 * DM);
  k_qkv_post<<<RR, 768, 0, stream>>>(qkvbuf, q_nw, k_nw, qbf, krotbf, out_kv);
  k_cache_prep<<<Bc * CACHE, 768, 0, stream>>>(cached, out_kv, krotbf);
  k_vt<<<Bc * NH * (KVL / 64), blk, 0, stream>>>(out_kv, vtbf);
  k_attn2<<<Bc * NH * (Nn / 64) * 2, blk, 0, stream>>>(qbf, krotbf, vtbf, Apart, lpart);
  k_attn_merge<<<Bc * NH * (Nn / 64), blk, 0, stream>>>(Apart, lpart, attnout);
  k_gemm_mfma<64, 3, false><<<dim3(DM / 64, RR / 128), blk, 0, stream>>>(
      attnout, wt_out, nullptr, xA, xB, DM, DM);
  // ---- Conv module ----
  k_rmsnorm2<true><<<RR, blk, 0, stream>>>(xB, conv_nw, abuf, DM);
  k_gemm_mfma<128, 0, true><<<dim3(2 * DM / 128, RR / 128), blk, 0, stream>>>(
      abuf, wt_pw1, pw1_b, nullptr, hbuf, DM, 2 * DM);
  k_zero<<<6, blk, 0, stream>>>(bn_stats, 2 * DM);
  k_dwconv2<<<dim3(DM / 64, Nn / 64, Bc), blk, 0, stream>>>(hbuf, dw_w, dw_b,
                                                            dwout, bn_stats);
  k_bn_apply<<<RR * DM / 256, blk, 0, stream>>>(dwout, bn_stats, bn_g, bn_b, bnout);
  k_gemm_mfma<64, 0, false><<<dim3(DM / 64, RR / 128), blk, 0, stream>>>(
      bnout, wt_pw2, pw2_b, nullptr, xA, DM, DM);
  // ---- FF2 ----
  k_rmsnorm2<true><<<RR, blk, 0, stream>>>(xA, ff2_nw, abuf, DM);
  k_gemm_mfma<128, 1, true><<<dim3(FFD / 128, RR / 128), blk, 0, stream>>>(
      abuf, wt_ff2w1, ff2_b1, nullptr, hbuf, DM, FFD);
  k_gemm_mfma<64, 2, false><<<dim3(DM / 64, RR / 128), blk, 0, stream>>>(
      hbuf, wt_ff2w2, ff2_b2, xA, xB, FFD, DM);
  // ---- final norm ----
  k_rmsnorm2<false><<<RR, blk, 0, stream>>>(xB, out_nw, out_x, DM);
}